// Round 6
// baseline (424.389 us; speedup 1.0000x reference)
//
#include <hip/hip_runtime.h>
#include <hip/hip_bf16.h>

#define N_ROWS 65536
#define DIMS 256
#define NCLS 64

// ---- ws float-index layout (~16.2 MiB) ----
#define PART     0        // [256][64][256] f32 per-block partials (128 src, 128 trg)
#define F_SUM_S  4194304  // [64][256]
#define F_SUM_T  4210688  // [64][256]
#define HIST     4227072  // int[128] (64 src, 64 trg)
#define ACC_OFF  4227200  // 64 doubles (byte off 16908800, 8-aligned)
#define BPACK    4227328  // bf16[12][8][64][8] = 24576 floats

typedef __attribute__((ext_vector_type(8))) short bf16x8;
typedef __attribute__((ext_vector_type(4))) float f32x4;

__device__ __forceinline__ short f2bf(float f) {
  unsigned u = __float_as_uint(f);
  u += 0x7fffu + ((u >> 16) & 1u);  // RNE
  return (short)(u >> 16);
}
__device__ __forceinline__ unsigned pk2(float x, float y) {
  union { __hip_bfloat162 h; unsigned u; } cv;
  cv.h = __float22bfloat162_rn(make_float2(x, y));  // v_cvt_pk_bf16_f32
  return cv.u;
}
__device__ __forceinline__ bf16x8 pack8(float4 lo, float4 hi) {
  union { unsigned u[4]; bf16x8 v; } cv;
  cv.u[0] = pk2(lo.x, lo.y);
  cv.u[1] = pk2(lo.z, lo.w);
  cv.u[2] = pk2(hi.x, hi.y);
  cv.u[3] = pk2(hi.z, hi.w);
  return cv.v;
}

__device__ __forceinline__ float wave_sum64(float v) {
#pragma unroll
  for (int m = 32; m > 0; m >>= 1) v += __shfl_xor(v, m, 64);
  return v;
}
__device__ __forceinline__ float seg_max16(float v) {
#pragma unroll
  for (int m = 8; m > 0; m >>= 1) v = fmaxf(v, __shfl_xor(v, m, 64));
  return v;
}
__device__ __forceinline__ float seg_sum16(float v) {
#pragma unroll
  for (int m = 8; m > 0; m >>= 1) v += __shfl_xor(v, m, 64);
  return v;
}

// ---------------------------------------------------------------------------
// Kernel 1: segment sums as one-hot MFMA GEMM. 256 blocks (128 src, 128 trg)
// x 512 rows. Per 64-row chunk: stage feat TRANSPOSED in LDS ([dim][row],
// pitch 72 bf16 -> even superbank spread for both b128 writes and B-frag
// reads), build one-hot A-frags in registers from labels, 32 MFMA. Zero
// atomics, zero RMW. Accumulators live in regs across all 8 chunks.
// ---------------------------------------------------------------------------
__global__ __launch_bounds__(256, 1) void seg_sum_mfma(
    const float* __restrict__ src_feat, const float* __restrict__ trg_feat,
    const int* __restrict__ src_label, const int* __restrict__ trg_label,
    float* __restrict__ ws_f) {
  __shared__ short ldsT[DIMS * 72];  // 36 KB, [dim][row] pitch 72
  __shared__ int lab[64];
  const int tid = threadIdx.x;
  const int wave = tid >> 6;
  const int lane = tid & 63;
  const int side = blockIdx.x >> 7;
  const int chunk = blockIdx.x & 127;
  const float* feat = side ? trg_feat : src_feat;
  const int* label = side ? trg_label : src_label;
  const int row0 = chunk * 512;

  f32x4 C[4][4];  // [mtile][ntile]; this wave's dims = wave*64 + nt*16 + (l&15)
#pragma unroll
  for (int mt = 0; mt < 4; ++mt)
#pragma unroll
    for (int nt = 0; nt < 4; ++nt) C[mt][nt] = (f32x4){0.f, 0.f, 0.f, 0.f};

  for (int ch = 0; ch < 8; ++ch) {
    const int rbase = row0 + ch * 64;
    if (tid < 64) lab[tid] = label[rbase + tid];
    // stage: wave w handles rows [16w,16w+16); lane owns one dim per slab
#pragma unroll
    for (int sl = 0; sl < 4; ++sl) {
#pragma unroll
      for (int o = 0; o < 2; ++o) {
        const int r8 = rbase + wave * 16 + o * 8;
        const int d = sl * 64 + lane;
        float v[8];
#pragma unroll
        for (int j = 0; j < 8; ++j)
          v[j] = feat[(size_t)(r8 + j) * DIMS + d];
        const bf16x8 pk = pack8(make_float4(v[0], v[1], v[2], v[3]),
                                make_float4(v[4], v[5], v[6], v[7]));
        *(bf16x8*)(ldsT + d * 72 + wave * 16 + o * 8) = pk;
      }
    }
    __syncthreads();

#pragma unroll
    for (int ks = 0; ks < 2; ++ks) {
      const int k0 = ks * 32 + (lane >> 4) * 8;
      int lbv[8];
#pragma unroll
      for (int j = 0; j < 8; ++j) lbv[j] = lab[k0 + j];
      bf16x8 A[4];
#pragma unroll
      for (int mt = 0; mt < 4; ++mt) {
        const int cls = mt * 16 + (lane & 15);
        union { unsigned u[4]; bf16x8 v; } au;
#pragma unroll
        for (int p = 0; p < 4; ++p)
          au.u[p] = (lbv[2 * p] == cls ? 0x3f80u : 0u) |
                    (lbv[2 * p + 1] == cls ? 0x3f800000u : 0u);
        A[mt] = au.v;
      }
#pragma unroll
      for (int nt = 0; nt < 4; ++nt) {
        const int d = wave * 64 + nt * 16 + (lane & 15);
        const bf16x8 B = *(const bf16x8*)(ldsT + d * 72 + k0);
#pragma unroll
        for (int mt = 0; mt < 4; ++mt)
          C[mt][nt] = __builtin_amdgcn_mfma_f32_16x16x32_bf16(A[mt], B, C[mt][nt], 0, 0, 0);
      }
    }
    __syncthreads();
  }

  // D mapping: class = mt*16 + (l>>4)*4 + r, dim = wave*64 + nt*16 + (l&15)
  float* pb = ws_f + PART + (size_t)blockIdx.x * 16384;
#pragma unroll
  for (int mt = 0; mt < 4; ++mt)
#pragma unroll
    for (int r = 0; r < 4; ++r) {
      const int cls = mt * 16 + (lane >> 4) * 4 + r;
#pragma unroll
      for (int nt = 0; nt < 4; ++nt)
        pb[cls * 256 + wave * 64 + nt * 16 + (lane & 15)] = C[mt][nt][r];
    }
}

// ---------------------------------------------------------------------------
// Kernel 2: label histogram (native int atomics, tiny). 128 blocks x 256 thr.
// ---------------------------------------------------------------------------
__global__ __launch_bounds__(256) void hist_kernel(
    const int* __restrict__ src_label, const int* __restrict__ trg_label,
    int* __restrict__ hist) {
  __shared__ int h[64];
  const int tid = threadIdx.x;
  if (tid < 64) h[tid] = 0;
  __syncthreads();
  const int side = blockIdx.x >> 6;
  const int* lb = side ? trg_label : src_label;
  const int base = (blockIdx.x & 63) * 1024 + tid * 4;
#pragma unroll
  for (int j = 0; j < 4; ++j) atomicAdd(&h[lb[base + j]], 1);
  __syncthreads();
  if (tid < 64) atomicAdd(&hist[side * 64 + tid], h[tid]);
}

// ---------------------------------------------------------------------------
// Kernel 3: reduce 128 chunk-partials per side -> F_SUM [c][256].
// 256 blocks x 256 thr; 32 float4 outputs/block, 8 threads split the k-sum.
// ---------------------------------------------------------------------------
__global__ __launch_bounds__(256) void reduce_kernel(float* __restrict__ ws_f) {
  __shared__ float4 red[256];
  const int tid = threadIdx.x;
  const int o = blockIdx.x * 32 + (tid & 31);  // float4 output 0..8191
  const int side = o >> 12;
  const int rem = o & 4095;  // c*64 + d4
  const int kseg = tid >> 5;  // 0..7
  const float4* p = (const float4*)(ws_f + PART) + (size_t)(side * 128) * 4096 + rem;
  float4 s = make_float4(0.f, 0.f, 0.f, 0.f);
  for (int k = kseg * 16; k < kseg * 16 + 16; ++k) {
    const float4 t = p[(size_t)k * 4096];
    s.x += t.x; s.y += t.y; s.z += t.z; s.w += t.w;
  }
  red[tid] = s;
  __syncthreads();
  if (tid < 32) {
#pragma unroll
    for (int m = 1; m < 8; ++m) {
      const float4 t = red[tid + 32 * m];
      s.x += t.x; s.y += t.y; s.z += t.z; s.w += t.w;
    }
    ((float4*)(ws_f + (side ? F_SUM_T : F_SUM_S)))[rem] = s;
  }
}

// ---------------------------------------------------------------------------
// Kernel 4: means + B-fragment pack for mfma_f32_16x16x32_bf16.
// B frag: lane l holds u[class = tile*16 + (l&15)][k = s*32 + (l>>4)*8 + j].
// ---------------------------------------------------------------------------
__global__ __launch_bounds__(64) void pack_kernel(float* __restrict__ ws_f) {
  const int bx = blockIdx.x;  // mat*4 + tile
  const int mat = bx >> 2;
  const int tile = bx & 3;
  const int lane = threadIdx.x;
  const int c = tile * 16 + (lane & 15);

  const int* hist = (const int*)(ws_f + HIST);
  const float cs = (float)hist[c];
  const float ct = (float)hist[64 + c];
  const float rs = 1.f / cs, rt = 1.f / ct, rst = 1.f / (cs + ct);

  bf16x8* out = (bf16x8*)(ws_f + BPACK);
#pragma unroll
  for (int s = 0; s < 8; ++s) {
    const int k0 = s * 32 + (lane >> 4) * 8;
    bf16x8 v;
#pragma unroll
    for (int j = 0; j < 8; ++j) {
      const float ss = ws_f[F_SUM_S + c * 256 + k0 + j];
      const float st = ws_f[F_SUM_T + c * 256 + k0 + j];
      float u;
      if (mat == 0) u = ss * rs;
      else if (mat == 1) u = st * rt;
      else u = (ss + st) * rst;
      v[j] = f2bf(u);
    }
    out[(bx * 8 + s) * 64 + lane] = v;
  }
}

// ---------------------------------------------------------------------------
// Kernel 5: MFMA logits + fused softmax/KL + reduce.
// 512 blocks x 512 thr. ALL 96 KB of B staged ONCE into LDS, then a
// barrier-free row loop: 2 iters x 8 waves x 16 rows. A: 16-load burst
// (single latency exposure; __launch_bounds__(512,1) -> 256 VGPR budget).
// ---------------------------------------------------------------------------
__global__ __launch_bounds__(512, 1) void main_kernel(
    const float* __restrict__ src_feat, const float* __restrict__ trg_feat,
    const float* __restrict__ ws_f, double* __restrict__ acc) {
  __shared__ bf16x8 bsh[6144];  // 96 KB
  __shared__ float bsum[8];
  const int tid = threadIdx.x;
  const int wave = tid >> 6;
  const int lane = tid & 63;

  const bf16x8* bp = (const bf16x8*)(ws_f + BPACK);
#pragma unroll
  for (int i = 0; i < 12; ++i) bsh[tid + 512 * i] = bp[tid + 512 * i];
  __syncthreads();

  float total = 0.f;
#pragma unroll 1
  for (int it = 0; it < 2; ++it) {
    const int tile = blockIdx.x * 16 + it * 8 + wave;
    const int row0 = tile * 16;
    const float* base = (row0 < N_ROWS)
                            ? src_feat + (size_t)row0 * DIMS
                            : trg_feat + (size_t)(row0 - N_ROWS) * DIMS;
    const float* ap = base + (lane & 15) * DIMS + (lane >> 4) * 8;

    float4 lo[8], hi[8];
#pragma unroll
    for (int s = 0; s < 8; ++s) {
      lo[s] = *(const float4*)(ap + s * 32);
      hi[s] = *(const float4*)(ap + s * 32 + 4);
    }
    bf16x8 a[8];
#pragma unroll
    for (int s = 0; s < 8; ++s) a[s] = pack8(lo[s], hi[s]);

    f32x4 C[12];
#pragma unroll
    for (int m = 0; m < 12; ++m) C[m] = (f32x4){0.f, 0.f, 0.f, 0.f};

#pragma unroll
    for (int s = 0; s < 8; ++s)
#pragma unroll
      for (int mt = 0; mt < 12; ++mt)
        C[mt] = __builtin_amdgcn_mfma_f32_16x16x32_bf16(
            a[s], bsh[(mt * 8 + s) * 64 + lane], C[mt], 0, 0, 0);

    // D mapping: row = (lane>>4)*4 + r, class = t*16 + (lane&15).
#pragma unroll
    for (int r = 0; r < 4; ++r) {
      float va[4], vb[4], vc[4];
#pragma unroll
      for (int t = 0; t < 4; ++t) {
        va[t] = C[t][r];
        vb[t] = C[4 + t][r];
        vc[t] = C[8 + t][r];
      }
      float ma = fmaxf(fmaxf(va[0], va[1]), fmaxf(va[2], va[3]));
      float mb = fmaxf(fmaxf(vb[0], vb[1]), fmaxf(vb[2], vb[3]));
      float mc = fmaxf(fmaxf(vc[0], vc[1]), fmaxf(vc[2], vc[3]));
      ma = seg_max16(ma); mb = seg_max16(mb); mc = seg_max16(mc);
      float ea[4], eb[4], ec[4];
      float sa = 0.f, sb = 0.f, sc = 0.f;
#pragma unroll
      for (int t = 0; t < 4; ++t) {
        ea[t] = __expf(va[t] - ma); sa += ea[t];
        eb[t] = __expf(vb[t] - mb); sb += eb[t];
        ec[t] = __expf(vc[t] - mc); sc += ec[t];
      }
      sa = seg_sum16(sa); sb = seg_sum16(sb); sc = seg_sum16(sc);
      const float La = ma + __logf(sa);
      const float Lb = mb + __logf(sb);
      const float Lc = mc + __logf(sc);
      const float isa = 1.f / sa, isb = 1.f / sb, isc = 1.f / sc;
#pragma unroll
      for (int t = 0; t < 4; ++t) {
        const float la = va[t] - La, lb = vb[t] - Lb, lc = vc[t] - Lc;
        const float pa = ea[t] * isa, pb = eb[t] * isb, pc = ec[t] * isc;
        total += pa * ((la - lb) + (la - lc)) + pb * ((lb - la) + (lb - lc)) +
                 pc * ((lc - la) + (lc - lb));
      }
    }
  }

  total = wave_sum64(total);
  if (lane == 0) bsum[wave] = total;
  __syncthreads();
  if (tid == 0) {
    double t = 0.0;
#pragma unroll
    for (int w = 0; w < 8; ++w) t += (double)bsum[w];
    atomicAdd(&acc[blockIdx.x & 63], t);
  }
}

// final = sum_of_6_kl_sums / (6 * 2N * C)
__global__ void finalize_kernel(const double* __restrict__ acc,
                                float* __restrict__ out) {
  double s = 0.0;
#pragma unroll
  for (int i = 0; i < 64; ++i) s += acc[i];
  out[0] = (float)(s / 50331648.0);  // 6 * 131072 * 64
}

extern "C" void kernel_launch(void* const* d_in, const int* in_sizes, int n_in,
                              void* d_out, int out_size, void* d_ws, size_t ws_size,
                              hipStream_t stream) {
  const float* src_feat = (const float*)d_in[0];
  const float* trg_feat = (const float*)d_in[1];
  const int* src_label = (const int*)d_in[2];
  const int* trg_label = (const int*)d_in[3];
  // d_in[4] (trg_feat_un) unused by the reference loss.
  float* ws_f = (float*)d_ws;
  int* hist = (int*)(ws_f + HIST);
  double* acc = (double*)(ws_f + ACC_OFF);
  float* out = (float*)d_out;

  // zero hist (128 ints) + acc (64 doubles) — contiguous 1 KB
  hipMemsetAsync((void*)(ws_f + HIST), 0, 256 * sizeof(float), stream);

  seg_sum_mfma<<<256, 256, 0, stream>>>(src_feat, trg_feat, src_label,
                                        trg_label, ws_f);
  hist_kernel<<<128, 256, 0, stream>>>(src_label, trg_label, hist);
  reduce_kernel<<<256, 256, 0, stream>>>(ws_f);
  pack_kernel<<<12, 64, 0, stream>>>(ws_f);
  main_kernel<<<512, 512, 0, stream>>>(src_feat, trg_feat, ws_f, acc);
  finalize_kernel<<<1, 1, 0, stream>>>(acc, out);
}